// Round 8
// baseline (107.566 us; speedup 1.0000x reference)
//
#include <hip/hip_runtime.h>

#define T_MAX 1024
#define N_NODES 512
#define FEAT 512
#define BATCH_B 4

// Two waves per (b, t): wave-half h owns features [h*256, h*256+256),
// one float4 per lane. Block = 256 threads = 4 waves = 2 tokens.
//
// Phase 1: ballot + popcount-prefix compacts matched node indices into a
//          per-wave LDS list in ascending-n (reference) order.
// Phase 2: counted gather loop, 4 independent float4 loads per iteration
//          (4x memory-level parallelism vs. the serialized ballot-walk).
//          Tail slots select a safe duplicate index and are zeroed with
//          exact fmaf(0/1, ...).
__global__ __launch_bounds__(256) void node_embed_kernel(
    const int* __restrict__ tokens,        // [B*T]
    const int* __restrict__ starts,        // [B*N]
    const int* __restrict__ ends,          // [B*N]
    const float* __restrict__ embed_tok,   // [VOCAB, F]
    const float* __restrict__ embed_node,  // [N, F]
    const float* __restrict__ pos_emb,     // [T, F]
    float* __restrict__ out)               // [B*T, F]
{
    const int wave = threadIdx.x >> 6;              // 0..3
    const int lane = threadIdx.x & 63;
    const int bt   = blockIdx.x * 2 + (wave >> 1);  // 0 .. B*T-1
    const int half = wave & 1;
    const int b    = bt >> 10;
    const int t    = bt & (T_MAX - 1);

    const int tok = tokens[bt];
    const int f   = half * 256 + lane * 4;

    // Issue the (L3-latency) token row and pos row loads early; they are
    // consumed only at the final merge, off the gather critical path.
    const float4 tv = *reinterpret_cast<const float4*>(embed_tok + (size_t)tok * FEAT + f);
    const float4 pe = *reinterpret_cast<const float4*>(pos_emb + (size_t)t * FEAT + f);

    // ---- Phase 1: compact matched node list into LDS (per wave) ----
    __shared__ int list[4][N_NODES];
    int* __restrict__ L = list[wave];

    const int* __restrict__ sb = starts + b * N_NODES;
    const int* __restrict__ eb = ends   + b * N_NODES;

    int count = 0;
    #pragma unroll
    for (int r = 0; r < N_NODES / 64; ++r) {
        const int n = (r << 6) + lane;
        const bool hit = (sb[n] <= t) && (t <= eb[n]);
        const unsigned long long m = __ballot(hit);
        if (hit) {
            const int pre = __popcll(m & ((1ull << lane) - 1ull));
            L[count + pre] = n;
        }
        count += __popcll(m);
    }
    // Per-wave LDS producer->consumer; compiler inserts lgkmcnt wait.

    // ---- Phase 2: batched gather, 4 rows in flight ----
    float4 acc = make_float4(0.f, 0.f, 0.f, 0.f);
    const float* __restrict__ nb = embed_node + f;

    for (int i = 0; i < count; i += 4) {
        const int i0 = L[i];
        const int r1 = L[(i + 1 < count) ? i + 1 : i];
        const int r2 = L[(i + 2 < count) ? i + 2 : i];
        const int r3 = L[(i + 3 < count) ? i + 3 : i];
        const float w1 = (i + 1 < count) ? 1.f : 0.f;
        const float w2 = (i + 2 < count) ? 1.f : 0.f;
        const float w3 = (i + 3 < count) ? 1.f : 0.f;

        const float4 v0 = *reinterpret_cast<const float4*>(nb + (size_t)i0 * FEAT);
        const float4 v1 = *reinterpret_cast<const float4*>(nb + (size_t)r1 * FEAT);
        const float4 v2 = *reinterpret_cast<const float4*>(nb + (size_t)r2 * FEAT);
        const float4 v3 = *reinterpret_cast<const float4*>(nb + (size_t)r3 * FEAT);

        acc.x += v0.x; acc.y += v0.y; acc.z += v0.z; acc.w += v0.w;
        acc.x = fmaf(w1, v1.x, acc.x); acc.y = fmaf(w1, v1.y, acc.y);
        acc.z = fmaf(w1, v1.z, acc.z); acc.w = fmaf(w1, v1.w, acc.w);
        acc.x = fmaf(w2, v2.x, acc.x); acc.y = fmaf(w2, v2.y, acc.y);
        acc.z = fmaf(w2, v2.z, acc.z); acc.w = fmaf(w2, v2.w, acc.w);
        acc.x = fmaf(w3, v3.x, acc.x); acc.y = fmaf(w3, v3.y, acc.y);
        acc.z = fmaf(w3, v3.z, acc.z); acc.w = fmaf(w3, v3.w, acc.w);
    }

    // ---- Merge + store ----
    acc.x += tv.x + pe.x; acc.y += tv.y + pe.y;
    acc.z += tv.z + pe.z; acc.w += tv.w + pe.w;
    *reinterpret_cast<float4*>(out + (size_t)bt * FEAT + f) = acc;
}

extern "C" void kernel_launch(void* const* d_in, const int* in_sizes, int n_in,
                              void* d_out, int out_size, void* d_ws, size_t ws_size,
                              hipStream_t stream) {
    const int*   tokens     = (const int*)d_in[0];
    const int*   starts     = (const int*)d_in[1];
    const int*   ends       = (const int*)d_in[2];
    const float* embed_tok  = (const float*)d_in[3];
    const float* embed_node = (const float*)d_in[4];
    const float* pos_emb    = (const float*)d_in[5];
    float*       out        = (float*)d_out;

    // 2 tokens per block, 2 waves per token.
    node_embed_kernel<<<dim3(BATCH_B * T_MAX / 2), dim3(256), 0, stream>>>(
        tokens, starts, ends, embed_tok, embed_node, pos_emb, out);
}